// Round 1
// baseline (1118.122 us; speedup 1.0000x reference)
//
#include <hip/hip_runtime.h>
#include <hip/hip_bf16.h>

#define NG 4
#define ID 128
#define HD 128
#define TH 384      // 3*HD
#define NB 32
#define NT 1000
#define XW (NG*ID)  // 512
#define OW (NG*HD)  // 512

// ---------------- Phase 1: gi[b,t,g,0:384] = x[b,t,g*128:+128] @ w_ih[g]^T + b_ih[g]
// stored bf16 in d_ws. grid (500, 3, 4), block 256.
__global__ __launch_bounds__(256) void gi_gemm(
    const float* __restrict__ x,
    const float* __restrict__ w_ih,
    const float* __restrict__ b_ih,
    __hip_bfloat16* __restrict__ gi)
{
    __shared__ float As[64][68];    // [m][k], pad 68 to break bank stride
    __shared__ float Bs[64][132];   // [k][n], pad 132
    const int t    = threadIdx.x;
    const int c    = t & 15;        // col group
    const int r    = t >> 4;        // row group
    const int row0 = blockIdx.x * 64;
    const int n0t  = blockIdx.y * 128;
    const int g    = blockIdx.z;
    const int m0   = r * 4;
    const int n0   = c * 8;

    float acc[4][8];
    #pragma unroll
    for (int i = 0; i < 4; ++i)
        #pragma unroll
        for (int u = 0; u < 8; ++u) acc[i][u] = 0.f;

    for (int ks = 0; ks < 2; ++ks) {
        // A tile: 64 rows x 64 k (fp32, coalesced, row-major LDS)
        #pragma unroll
        for (int i = 0; i < 4; ++i) {
            int f = t + i * 256;        // float4 id
            int m = f >> 4, kq = f & 15;
            float4 v = *reinterpret_cast<const float4*>(
                &x[(size_t)(row0 + m) * XW + g * ID + ks * 64 + kq * 4]);
            *reinterpret_cast<float4*>(&As[m][kq * 4]) = v;
        }
        // B tile: 128 n-rows x 64 k, transposed into Bs[k][n]
        #pragma unroll
        for (int i = 0; i < 8; ++i) {
            int f = t + i * 256;
            int n = f >> 4, kq = f & 15;
            float4 v = *reinterpret_cast<const float4*>(
                &w_ih[(size_t)(g * TH + n0t + n) * ID + ks * 64 + kq * 4]);
            Bs[kq * 4 + 0][n] = v.x;
            Bs[kq * 4 + 1][n] = v.y;
            Bs[kq * 4 + 2][n] = v.z;
            Bs[kq * 4 + 3][n] = v.w;
        }
        __syncthreads();
        #pragma unroll 8
        for (int k = 0; k < 64; ++k) {
            float aa[4];
            #pragma unroll
            for (int i = 0; i < 4; ++i) aa[i] = As[m0 + i][k];
            float bb[8];
            *reinterpret_cast<float4*>(&bb[0]) =
                *reinterpret_cast<const float4*>(&Bs[k][n0]);
            *reinterpret_cast<float4*>(&bb[4]) =
                *reinterpret_cast<const float4*>(&Bs[k][n0 + 4]);
            #pragma unroll
            for (int i = 0; i < 4; ++i)
                #pragma unroll
                for (int u = 0; u < 8; ++u)
                    acc[i][u] = fmaf(aa[i], bb[u], acc[i][u]);
        }
        __syncthreads();
    }

    float bias[8];
    #pragma unroll
    for (int u = 0; u < 8; ++u) bias[u] = b_ih[g * TH + n0t + n0 + u];
    #pragma unroll
    for (int i = 0; i < 4; ++i) {
        int row = row0 + m0 + i;
        union { __hip_bfloat16 h[8]; uint4 u4; } pk;
        #pragma unroll
        for (int u = 0; u < 8; ++u)
            pk.h[u] = __float2bfloat16(acc[i][u] + bias[u]);
        *reinterpret_cast<uint4*>(
            &gi[((size_t)row * NG + g) * TH + n0t + n0]) = pk.u4;
    }
}

// ---------------- Phase 2: sequential GRU recurrence.
// One 384-thread workgroup per (b,g); thread j owns w_hh row j in VGPRs.
__global__ __launch_bounds__(384) void gru_rec(
    const __hip_bfloat16* __restrict__ gi,
    const float* __restrict__ w_hh,
    const float* __restrict__ b_hh,
    float* __restrict__ out)
{
    __shared__ float4 h4[32];       // h state, fp32, 16B-aligned for float4 reads
    __shared__ float s_lds[TH];     // gh (= h@w_hh^T + b_hh)
    __shared__ float g_lds[TH];     // gi_t
    float* h_lds = reinterpret_cast<float*>(h4);

    const int j = threadIdx.x;      // 0..383 : output row of w_hh
    const int b = blockIdx.x >> 2;
    const int g = blockIdx.x & 3;

    // load my w_hh row into 128 VGPRs (one-time, amortized over 1000 steps)
    float w[128];
    {
        const float4* wp = reinterpret_cast<const float4*>(
            &w_hh[(size_t)(g * TH + j) * HD]);
        #pragma unroll
        for (int k = 0; k < 32; ++k) {
            float4 v = wp[k];
            w[4*k+0] = v.x; w[4*k+1] = v.y; w[4*k+2] = v.z; w[4*k+3] = v.w;
        }
    }
    const float bhh = b_hh[g * TH + j];

    if (j < HD) h_lds[j] = 0.f;
    __syncthreads();

    const __hip_bfloat16* gp = gi + ((size_t)b * NT * NG + g) * TH + j;
    float gnext = __bfloat162float(gp[0]);          // prefetch t=0
    float* op = out + (size_t)b * NT * OW + g * HD + j;  // used only when j<128

    for (int tt = 0; tt < NT; ++tt) {
        float gv = gnext;
        int tn = (tt + 1 < NT) ? tt + 1 : NT - 1;
        gnext = __bfloat162float(gp[(size_t)tn * (NG * TH)]);  // prefetch next step

        // gh[j] = b_hh[j] + sum_k w_hh[j][k] * h[k]   (h broadcast from LDS)
        float acc = bhh;
        #pragma unroll
        for (int k = 0; k < 32; ++k) {
            float4 hv = h4[k];
            acc = fmaf(w[4*k+0], hv.x, acc);
            acc = fmaf(w[4*k+1], hv.y, acc);
            acc = fmaf(w[4*k+2], hv.z, acc);
            acc = fmaf(w[4*k+3], hv.w, acc);
        }
        s_lds[j] = acc;
        g_lds[j] = gv;
        __syncthreads();

        if (j < HD) {
            float xr = g_lds[j]        + s_lds[j];
            float xz = g_lds[HD + j]   + s_lds[HD + j];
            float rr = 1.f / (1.f + __expf(-xr));
            float zz = 1.f / (1.f + __expf(-xz));
            float xn = g_lds[2*HD + j] + rr * s_lds[2*HD + j];
            xn = fminf(fmaxf(xn, -15.f), 15.f);
            float e2 = __expf(2.f * xn);
            float nn = (e2 - 1.f) / (e2 + 1.f);     // tanh
            float hp = h_lds[j];
            float hn = (1.f - zz) * nn + zz * hp;
            h_lds[j] = hn;
            op[(size_t)tt * OW] = hn;
        }
        __syncthreads();
    }
}

extern "C" void kernel_launch(void* const* d_in, const int* in_sizes, int n_in,
                              void* d_out, int out_size, void* d_ws, size_t ws_size,
                              hipStream_t stream) {
    const float* x    = (const float*)d_in[0];
    const float* w_ih = (const float*)d_in[1];
    const float* w_hh = (const float*)d_in[2];
    const float* b_ih = (const float*)d_in[3];
    const float* b_hh = (const float*)d_in[4];
    float* out = (float*)d_out;
    __hip_bfloat16* gi = (__hip_bfloat16*)d_ws;   // [B*T, G, 384] bf16 = 98.3 MB

    dim3 g1(500, 3, NG);
    gi_gemm<<<g1, 256, 0, stream>>>(x, w_ih, b_ih, gi);
    gru_rec<<<NB * NG, 384, 0, stream>>>(gi, w_hh, b_hh, out);
}

// Round 3
// 964.616 us; speedup vs baseline: 1.1591x; 1.1591x over previous
//
#include <hip/hip_runtime.h>
#include <hip/hip_bf16.h>

#define NG 4
#define ID 128
#define HD 128
#define TH 384      // 3*HD
#define NB 32
#define NT 1000
#define XW (NG*ID)  // 512
#define OW (NG*HD)  // 512

typedef __attribute__((ext_vector_type(8))) short v8s;
typedef __attribute__((ext_vector_type(4))) float v4f;

__device__ __forceinline__ short f2bf(float x) {
    __hip_bfloat16 h = __float2bfloat16(x);
    return *reinterpret_cast<short*>(&h);
}
__device__ __forceinline__ float bf2f(ushort u) {
    union { unsigned int i; float f; } c; c.i = ((unsigned int)u) << 16; return c.f;
}

// ---------------- Phase 1: gi[b,t,g,0:384] = x[b,t,g*128:+128] @ w_ih[g]^T + b_ih[g]
// stored bf16 in d_ws. grid (500, 3, 4), block 256.
__global__ __launch_bounds__(256) void gi_gemm(
    const float* __restrict__ x,
    const float* __restrict__ w_ih,
    const float* __restrict__ b_ih,
    __hip_bfloat16* __restrict__ gi)
{
    __shared__ float As[64][68];
    __shared__ float Bs[64][132];
    const int t    = threadIdx.x;
    const int c    = t & 15;
    const int r    = t >> 4;
    const int row0 = blockIdx.x * 64;
    const int n0t  = blockIdx.y * 128;
    const int g    = blockIdx.z;
    const int m0   = r * 4;
    const int n0   = c * 8;

    float acc[4][8];
    #pragma unroll
    for (int i = 0; i < 4; ++i)
        #pragma unroll
        for (int u = 0; u < 8; ++u) acc[i][u] = 0.f;

    for (int ks = 0; ks < 2; ++ks) {
        #pragma unroll
        for (int i = 0; i < 4; ++i) {
            int f = t + i * 256;
            int m = f >> 4, kq = f & 15;
            float4 v = *reinterpret_cast<const float4*>(
                &x[(size_t)(row0 + m) * XW + g * ID + ks * 64 + kq * 4]);
            *reinterpret_cast<float4*>(&As[m][kq * 4]) = v;
        }
        #pragma unroll
        for (int i = 0; i < 8; ++i) {
            int f = t + i * 256;
            int n = f >> 4, kq = f & 15;
            float4 v = *reinterpret_cast<const float4*>(
                &w_ih[(size_t)(g * TH + n0t + n) * ID + ks * 64 + kq * 4]);
            Bs[kq * 4 + 0][n] = v.x;
            Bs[kq * 4 + 1][n] = v.y;
            Bs[kq * 4 + 2][n] = v.z;
            Bs[kq * 4 + 3][n] = v.w;
        }
        __syncthreads();
        #pragma unroll 8
        for (int k = 0; k < 64; ++k) {
            float aa[4];
            #pragma unroll
            for (int i = 0; i < 4; ++i) aa[i] = As[m0 + i][k];
            float bb[8];
            *reinterpret_cast<float4*>(&bb[0]) =
                *reinterpret_cast<const float4*>(&Bs[k][n0]);
            *reinterpret_cast<float4*>(&bb[4]) =
                *reinterpret_cast<const float4*>(&Bs[k][n0 + 4]);
            #pragma unroll
            for (int i = 0; i < 4; ++i)
                #pragma unroll
                for (int u = 0; u < 8; ++u)
                    acc[i][u] = fmaf(aa[i], bb[u], acc[i][u]);
        }
        __syncthreads();
    }

    float bias[8];
    #pragma unroll
    for (int u = 0; u < 8; ++u) bias[u] = b_ih[g * TH + n0t + n0 + u];
    #pragma unroll
    for (int i = 0; i < 4; ++i) {
        int row = row0 + m0 + i;
        union { __hip_bfloat16 h[8]; uint4 u4; } pk;
        #pragma unroll
        for (int u = 0; u < 8; ++u)
            pk.h[u] = __float2bfloat16(acc[i][u] + bias[u]);
        *reinterpret_cast<uint4*>(
            &gi[((size_t)row * NG + g) * TH + n0t + n0]) = pk.u4;
    }
}

// ---------------- Phase 2: MFMA-batched GRU recurrence.
// One WG per (g, batch-chunk of 4): grid 32, block 512 (8 waves).
// Wave w owns m-tiles {w, w+8, w+16} => r/z/n gate rows 16w..16w+15.
__global__ __launch_bounds__(512) void gru_rec_mfma(
    const __hip_bfloat16* __restrict__ gi,
    const float* __restrict__ w_hh,
    const float* __restrict__ b_hh,
    float* __restrict__ out)
{
    __shared__ ushort h_lds[16][152];      // [batch n][k], 304B rows
    __shared__ ushort gi_lds[2][4][392];   // [buf][batch][384 pad 392]
    __shared__ float  gh_lds[3][4][132];   // [gate][batch][j pad 132]

    const int tid = threadIdx.x;
    const int w   = tid >> 6;          // wave 0..7
    const int l   = tid & 63;
    const int g   = blockIdx.x & 3;
    const int b0  = (blockIdx.x >> 2) * 4;

    const int lr  = l & 15;            // A-row / B-col within tile
    const int lq  = l >> 4;            // k-chunk quad / acc row quad

    // ---- load w_hh A-fragments (bf16) once: 3 m-tiles x 4 k-frags
    v8s a[3][4];
    #pragma unroll
    for (int i = 0; i < 3; ++i) {
        int mrow = (w + 8 * i) * 16 + lr;            // 0..383
        #pragma unroll
        for (int kf = 0; kf < 4; ++kf) {
            const float* p = &w_hh[(size_t)(g * TH + mrow) * HD + kf * 32 + lq * 8];
            float4 f0 = *reinterpret_cast<const float4*>(p);
            float4 f1 = *reinterpret_cast<const float4*>(p + 4);
            v8s av;
            av[0] = f2bf(f0.x); av[1] = f2bf(f0.y); av[2] = f2bf(f0.z); av[3] = f2bf(f0.w);
            av[4] = f2bf(f1.x); av[5] = f2bf(f1.y); av[6] = f2bf(f1.z); av[7] = f2bf(f1.w);
            a[i][kf] = av;
        }
    }

    // ---- gate-lane identity: lane l -> (j = 16w + jl, batch nb)
    const int jl = l >> 2;
    const int nb = l & 3;
    const int j  = w * 16 + jl;
    const float bR = b_hh[g * TH + j];
    const float bZ = b_hh[g * TH + 128 + j];
    const float bN = b_hh[g * TH + 256 + j];
    float h_prev = 0.f;
    float* outp = out + (size_t)(b0 + nb) * NT * OW + g * HD + j;

    // ---- zero h state (all 16 cols so unused B-frag lanes read 0)
    {
        unsigned int* hz = reinterpret_cast<unsigned int*>(&h_lds[0][0]);
        for (int i2 = tid; i2 < 16 * 152 / 2; i2 += 512) hz[i2] = 0u;
    }

    // ---- gi staging: thread tid<192 moves 16B: batch bb = tid/48, segment seg = tid%48
    const int bb  = tid / 48;
    const int seg = tid - bb * 48;        // 48 segs * 8 shorts = 384 = TH
    const __hip_bfloat16* gbase = gi + ((size_t)(b0 + bb) * NT * NG + g) * TH + seg * 8;
    const bool stager = (tid < 192);

    if (stager) {
        uint4 v = *reinterpret_cast<const uint4*>(gbase);   // t = 0
        *reinterpret_cast<uint4*>(&gi_lds[0][bb][seg * 8]) = v;
    }
    __syncthreads();

    const char* hbytes = reinterpret_cast<const char*>(&h_lds[0][0]);

    for (int t = 0; t < NT; ++t) {
        const int buf = t & 1;
        // prefetch gi for t+1 (global -> reg)
        uint4 pre;
        const bool do_pre = stager && (t + 1 < NT);
        if (do_pre)
            pre = *reinterpret_cast<const uint4*>(gbase + (size_t)(t + 1) * (NG * TH));

        // ---- B fragments from h_lds: B[k][n=lr] = h_lds[lr][k], k = kf*32 + lq*8 + e
        v8s bfr[4];
        #pragma unroll
        for (int kf = 0; kf < 4; ++kf)
            bfr[kf] = *reinterpret_cast<const v8s*>(
                hbytes + lr * 304 + kf * 64 + lq * 16);

        // ---- MFMA: gh = w_hh . h
        v4f acc0 = {0.f, 0.f, 0.f, 0.f}, acc1 = acc0, acc2 = acc0;
        #pragma unroll
        for (int kf = 0; kf < 4; ++kf) {
            acc0 = __builtin_amdgcn_mfma_f32_16x16x32_bf16(a[0][kf], bfr[kf], acc0, 0, 0, 0);
            acc1 = __builtin_amdgcn_mfma_f32_16x16x32_bf16(a[1][kf], bfr[kf], acc1, 0, 0, 0);
            acc2 = __builtin_amdgcn_mfma_f32_16x16x32_bf16(a[2][kf], bfr[kf], acc2, 0, 0, 0);
        }

        // ---- scatter gh to LDS: D[m=lq*4+reg][n=lr] -> gh_lds[gate][n][16w+4lq+reg]
        if (lr < 4) {
            int jb = w * 16 + lq * 4;
            *reinterpret_cast<v4f*>(&gh_lds[0][lr][jb]) = acc0;
            *reinterpret_cast<v4f*>(&gh_lds[1][lr][jb]) = acc1;
            *reinterpret_cast<v4f*>(&gh_lds[2][lr][jb]) = acc2;
        }
        __syncthreads();   // gh visible; also fences B-frag reads before h overwrite

        // ---- gates: one (j, nb) element per lane
        float ghr = gh_lds[0][nb][j] + bR;
        float ghz = gh_lds[1][nb][j] + bZ;
        float ghn = gh_lds[2][nb][j] + bN;
        float iR = bf2f(gi_lds[buf][nb][j]);
        float iZ = bf2f(gi_lds[buf][nb][128 + j]);
        float iN = bf2f(gi_lds[buf][nb][256 + j]);

        float rr = 1.f / (1.f + __expf(-(iR + ghr)));
        float zz = 1.f / (1.f + __expf(-(iZ + ghz)));
        float xn = iN + rr * ghn;
        xn = fminf(fmaxf(xn, -15.f), 15.f);
        float e2 = __expf(2.f * xn);
        float nn = (e2 - 1.f) / (e2 + 1.f);
        float hn = (1.f - zz) * nn + zz * h_prev;
        h_prev = hn;

        // ---- h -> LDS bf16 (pair-merge via shfl so writes are b32)
        float hp2 = __shfl_xor(hn, 4, 64);     // partner has j^1, same nb
        if ((jl & 1) == 0) {
            unsigned int wv = (unsigned int)(unsigned short)f2bf(hn) |
                              ((unsigned int)(unsigned short)f2bf(hp2) << 16);
            *reinterpret_cast<unsigned int*>(&h_lds[nb][j]) = wv;
        }
        outp[(size_t)t * OW] = hn;

        // ---- write prefetched gi into other buffer
        if (do_pre)
            *reinterpret_cast<uint4*>(&gi_lds[buf ^ 1][bb][seg * 8]) = pre;

        __syncthreads();   // h + gi visible for next step
    }
}

extern "C" void kernel_launch(void* const* d_in, const int* in_sizes, int n_in,
                              void* d_out, int out_size, void* d_ws, size_t ws_size,
                              hipStream_t stream) {
    const float* x    = (const float*)d_in[0];
    const float* w_ih = (const float*)d_in[1];
    const float* w_hh = (const float*)d_in[2];
    const float* b_ih = (const float*)d_in[3];
    const float* b_hh = (const float*)d_in[4];
    float* out = (float*)d_out;
    __hip_bfloat16* gi = (__hip_bfloat16*)d_ws;   // [B*T, G, 384] bf16 = 98.3 MB

    dim3 g1(500, 3, NG);
    gi_gemm<<<g1, 256, 0, stream>>>(x, w_ih, b_ih, gi);
    gru_rec_mfma<<<NB * NG / 4, 512, 0, stream>>>(gi, w_hh, b_hh, out);
}